// Round 2
// baseline (1406.115 us; speedup 1.0000x reference)
//
#include <hip/hip_runtime.h>
#include <math.h>

// GAT forward, fp32 baseline.
// Structure: CSR build (hist/scan/scatter) -> fc0 -> 2x [proj4 GEMM -> fused
// edge kernel (online softmax per dst node, one wave/node)] -> fc1+gelu -> fc2.
// Workspace: hA,hB,K,Q,V (5 * N*128 f32) + deg/rowp/cursor/csrc ints ~= 264MB.
// R1 fix: k_gemm4 inner loop was missing the kc*32 chunk offset on the A
// column index -> all 128x128 GEMMs wrong (absmax ~6). One-line fix.

__device__ __forceinline__ float gelu_f(float x) {
    float x3 = x * x * x;
    return 0.5f * x * (1.f + tanhf(0.7978845608028654f * (x + 0.044715f * x3)));
}

// ---------------- CSR build ----------------
__global__ void k_zero(int* __restrict__ p, int n) {
    int i = blockIdx.x * blockDim.x + threadIdx.x;
    if (i < n) p[i] = 0;
}

__global__ void k_hist(const int* __restrict__ dst, int* __restrict__ deg, int e) {
    int i = blockIdx.x * blockDim.x + threadIdx.x;
    if (i < e) atomicAdd(&deg[dst[i]], 1);
}

__global__ void k_scan(const int* __restrict__ deg, int* __restrict__ rowp,
                       int* __restrict__ cur, int n, int e) {
    __shared__ int sums[1024];
    int t = threadIdx.x;
    int chunk = (n + 1023) >> 10;
    int beg = t * chunk;
    int end = min(beg + chunk, n);
    int s = 0;
    for (int i = beg; i < end; ++i) s += deg[i];
    sums[t] = s;
    __syncthreads();
    for (int off = 1; off < 1024; off <<= 1) {
        int v = (t >= off) ? sums[t - off] : 0;
        __syncthreads();
        sums[t] += v;
        __syncthreads();
    }
    int run = sums[t] - s;  // exclusive prefix for this thread's chunk
    for (int i = beg; i < end; ++i) {
        rowp[i] = run;
        cur[i] = run;
        run += deg[i];
    }
    if (t == 0) rowp[n] = e;
}

__global__ void k_scatter(const int* __restrict__ src, const int* __restrict__ dst,
                          int* __restrict__ cur, int* __restrict__ csrc, int e) {
    int i = blockIdx.x * blockDim.x + threadIdx.x;
    if (i < e) {
        int p = atomicAdd(&cur[dst[i]], 1);
        csrc[p] = src[i];
    }
}

// ---------------- fc0: [N,16] @ [16,128] + b ----------------
__global__ __launch_bounds__(256) void k_fc0(const float* __restrict__ X,
                                             const float* __restrict__ W,
                                             const float* __restrict__ b,
                                             float* __restrict__ H, int n) {
    __shared__ float Ws[16 * 128];
    __shared__ float xs[2][16];
    int t = threadIdx.x;
#pragma unroll
    for (int i = 0; i < 8; ++i) Ws[t + i * 256] = W[t + i * 256];
    if (t < 32) {
        int nn = blockIdx.x * 2 + (t >> 4);
        xs[t >> 4][t & 15] = (nn < n) ? X[nn * 16 + (t & 15)] : 0.f;
    }
    __syncthreads();
    int nd = blockIdx.x * 2 + (t >> 7);
    if (nd < n) {
        int c = t & 127;
        float acc = b[c];
#pragma unroll
        for (int j = 0; j < 16; ++j) acc += xs[t >> 7][j] * Ws[j * 128 + c];
        H[nd * 128 + c] = acc;
    }
}

// ---------------- generic [N,128]@[128,128]+b, up to 4 matrices via blockIdx.y ----------------
// block 256, tile 64 rows x 128 cols, per-thread 8 rows x 4 cols.
__global__ __launch_bounds__(256) void k_gemm4(
    const float* __restrict__ A, int n,
    const float* __restrict__ W0, const float* __restrict__ b0, float* __restrict__ O0,
    const float* __restrict__ W1, const float* __restrict__ b1, float* __restrict__ O1,
    const float* __restrict__ W2, const float* __restrict__ b2, float* __restrict__ O2,
    const float* __restrict__ W3, const float* __restrict__ b3, float* __restrict__ O3,
    int act) {
    const float* W;
    const float* bias;
    float* O;
    int m = blockIdx.y;
    if (m == 0)      { W = W0; bias = b0; O = O0; }
    else if (m == 1) { W = W1; bias = b1; O = O1; }
    else if (m == 2) { W = W2; bias = b2; O = O2; }
    else             { W = W3; bias = b3; O = O3; }

    __shared__ float As[64 * 128];   // 32 KB
    __shared__ float Ws[32 * 128];   // 16 KB
    int t = threadIdx.x;
    int rbase = blockIdx.x * 64;

    // stage A tile (rows rbase..rbase+63), coalesced float4
#pragma unroll
    for (int i = 0; i < 8; ++i) {
        int f = t * 4 + i * 1024;
        int r = f >> 7;
        float4 val = {0.f, 0.f, 0.f, 0.f};
        if (rbase + r < n) val = *(const float4*)&A[(size_t)(rbase + r) * 128 + (f & 127)];
        *(float4*)&As[f] = val;
    }

    float acc[8][4];
#pragma unroll
    for (int i = 0; i < 8; ++i)
#pragma unroll
        for (int j = 0; j < 4; ++j) acc[i][j] = 0.f;

    int cg = t & 31, rg = t >> 5;
    int c0 = cg * 4, r0 = rg * 8;

    for (int kc = 0; kc < 4; ++kc) {
        // stage W chunk rows [kc*32, kc*32+32)
#pragma unroll
        for (int i = 0; i < 4; ++i) {
            int f = t * 4 + i * 1024;
            *(float4*)&Ws[f] = *(const float4*)&W[kc * 32 * 128 + f];
        }
        __syncthreads();
#pragma unroll
        for (int k = 0; k < 32; ++k) {
            float4 w4 = *(float4*)&Ws[k * 128 + c0];
#pragma unroll
            for (int i = 0; i < 8; ++i) {
                float a = As[(r0 + i) * 128 + kc * 32 + k];
                acc[i][0] += a * w4.x;
                acc[i][1] += a * w4.y;
                acc[i][2] += a * w4.z;
                acc[i][3] += a * w4.w;
            }
        }
        __syncthreads();
    }

    float4 bb = *(const float4*)&bias[c0];
#pragma unroll
    for (int i = 0; i < 8; ++i) {
        int r = rbase + r0 + i;
        if (r < n) {
            float4 o;
            o.x = acc[i][0] + bb.x;
            o.y = acc[i][1] + bb.y;
            o.z = acc[i][2] + bb.z;
            o.w = acc[i][3] + bb.w;
            if (act) {
                o.x = gelu_f(o.x);
                o.y = gelu_f(o.y);
                o.z = gelu_f(o.z);
                o.w = gelu_f(o.w);
            }
            *(float4*)&O[(size_t)r * 128 + c0] = o;
        }
    }
}

// ---------------- fused edge phase: one wave per dst node ----------------
// lane l holds feature elements 2l,2l+1 -> lanes 0..31 = head 0, 32..63 = head 1.
// Online softmax over this node's edges; H (holds s = h@Ws+b) updated in place:
// H[d] = act(H[d] + res[d]).
__global__ void k_edge(const float* __restrict__ K, const float* __restrict__ Q,
                       const float* __restrict__ V, const int* __restrict__ rowp,
                       const int* __restrict__ csrc, float* __restrict__ H, int n,
                       int act) {
    int wid = (int)((blockIdx.x * blockDim.x + threadIdx.x) >> 6);
    int lane = threadIdx.x & 63;
    if (wid >= n) return;
    int e0 = rowp[wid], e1 = rowp[wid + 1];
    float2 q2 = *(const float2*)&Q[(size_t)wid * 128 + lane * 2];
    float m = -INFINITY;
    float denom = 0.f;
    float accx = 0.f, accy = 0.f;
    for (int eb = e0; eb < e1; eb += 64) {
        int cnt = min(64, e1 - eb);
        int sl = (eb + lane < e1) ? csrc[eb + lane] : 0;
        for (int j = 0; j < cnt; ++j) {
            int s = __shfl(sl, j);
            float2 k2 = *(const float2*)&K[(size_t)s * 128 + lane * 2];
            float sc = k2.x * q2.x + k2.y * q2.y;
            sc += __shfl_xor(sc, 1);
            sc += __shfl_xor(sc, 2);
            sc += __shfl_xor(sc, 4);
            sc += __shfl_xor(sc, 8);
            sc += __shfl_xor(sc, 16);
            // lanes 0..31 now hold head-0 score; 32..63 head-1 score
            float2 v2 = *(const float2*)&V[(size_t)s * 128 + lane * 2];
            if (sc > m) {
                float scale = __expf(m - sc);  // exp(-inf)=0 on first edge
                denom = denom * scale + 1.f;
                accx = accx * scale + v2.x;
                accy = accy * scale + v2.y;
                m = sc;
            } else {
                float p = __expf(sc - m);
                denom += p;
                accx += p * v2.x;
                accy += p * v2.y;
            }
        }
    }
    float inv = (denom > 0.f) ? 1.f / denom : 0.f;
    float2 s2 = *(float2*)&H[(size_t)wid * 128 + lane * 2];
    float ox = s2.x + accx * inv;
    float oy = s2.y + accy * inv;
    if (act) {
        ox = gelu_f(ox);
        oy = gelu_f(oy);
    }
    float2 o = {ox, oy};
    *(float2*)&H[(size_t)wid * 128 + lane * 2] = o;
}

// ---------------- fc2: [N,128]@[128,4]+b, one wave per node ----------------
__global__ void k_fc2(const float* __restrict__ H, const float* __restrict__ W,
                      const float* __restrict__ b, float* __restrict__ out, int n) {
    int wid = (int)((blockIdx.x * blockDim.x + threadIdx.x) >> 6);
    int lane = threadIdx.x & 63;
    if (wid >= n) return;
    float2 x2 = *(const float2*)&H[(size_t)wid * 128 + lane * 2];
    float4 wA = *(const float4*)&W[(lane * 2) * 4];
    float4 wB = *(const float4*)&W[(lane * 2 + 1) * 4];
    float a0 = x2.x * wA.x + x2.y * wB.x;
    float a1 = x2.x * wA.y + x2.y * wB.y;
    float a2 = x2.x * wA.z + x2.y * wB.z;
    float a3 = x2.x * wA.w + x2.y * wB.w;
#pragma unroll
    for (int off = 1; off < 64; off <<= 1) {
        a0 += __shfl_xor(a0, off);
        a1 += __shfl_xor(a1, off);
        a2 += __shfl_xor(a2, off);
        a3 += __shfl_xor(a3, off);
    }
    if (lane < 4) {
        float v = (lane == 0) ? a0 : (lane == 1) ? a1 : (lane == 2) ? a2 : a3;
        out[(size_t)wid * 4 + lane] = v + b[lane];
    }
}

extern "C" void kernel_launch(void* const* d_in, const int* in_sizes, int n_in,
                              void* d_out, int out_size, void* d_ws, size_t ws_size,
                              hipStream_t stream) {
    const float* x     = (const float*)d_in[0];
    const int*   src   = (const int*)d_in[1];
    const int*   dst   = (const int*)d_in[2];
    const float* fc0_w = (const float*)d_in[3];
    const float* fc0_b = (const float*)d_in[4];
    const float* Wk    = (const float*)d_in[5];
    const float* bk    = (const float*)d_in[6];
    const float* Wq    = (const float*)d_in[7];
    const float* bq    = (const float*)d_in[8];
    const float* Wv    = (const float*)d_in[9];
    const float* bv    = (const float*)d_in[10];
    const float* ws_w  = (const float*)d_in[11];
    const float* ws_b  = (const float*)d_in[12];
    const float* fc1_w = (const float*)d_in[13];
    const float* fc1_b = (const float*)d_in[14];
    const float* fc2_w = (const float*)d_in[15];
    const float* fc2_b = (const float*)d_in[16];

    int n = in_sizes[0] / 16;
    int e = in_sizes[1];

    float* hA  = (float*)d_ws;
    float* hB  = hA + (size_t)n * 128;
    float* Kb  = hB + (size_t)n * 128;
    float* Qb  = Kb + (size_t)n * 128;
    float* Vb  = Qb + (size_t)n * 128;
    int* deg   = (int*)(Vb + (size_t)n * 128);
    int* rowp  = deg + n;
    int* cur   = rowp + n + 1;
    int* csrc  = cur + n;

    // CSR build
    k_zero<<<(n + 255) / 256, 256, 0, stream>>>(deg, n);
    k_hist<<<(e + 255) / 256, 256, 0, stream>>>(dst, deg, e);
    k_scan<<<1, 1024, 0, stream>>>(deg, rowp, cur, n, e);
    k_scatter<<<(e + 255) / 256, 256, 0, stream>>>(src, dst, cur, csrc, e);

    // fc0
    k_fc0<<<(n + 1) / 2, 256, 0, stream>>>(x, fc0_w, fc0_b, hA, n);

    int gx = (n + 63) / 64;
    // layer 0: proj (k,q,v,s) then fused edge phase (+gelu)
    k_gemm4<<<dim3(gx, 4), 256, 0, stream>>>(hA, n, Wk, bk, Kb, Wq, bq, Qb, Wv, bv,
                                             Vb, ws_w, ws_b, hB, 0);
    k_edge<<<(n + 3) / 4, 256, 0, stream>>>(Kb, Qb, Vb, rowp, csrc, hB, n, 1);
    // layer 1
    k_gemm4<<<dim3(gx, 4), 256, 0, stream>>>(
        hB, n, Wk + 128 * 128, bk + 128, Kb, Wq + 128 * 128, bq + 128, Qb,
        Wv + 128 * 128, bv + 128, Vb, ws_w + 128 * 128, ws_b + 128, hA, 0);
    k_edge<<<(n + 3) / 4, 256, 0, stream>>>(Kb, Qb, Vb, rowp, csrc, hA, n, 0);

    // fc1 + gelu
    k_gemm4<<<dim3(gx, 1), 256, 0, stream>>>(hA, n, fc1_w, fc1_b, hB, fc1_w, fc1_b,
                                             hB, fc1_w, fc1_b, hB, fc1_w, fc1_b, hB, 1);
    // fc2
    k_fc2<<<(n + 3) / 4, 256, 0, stream>>>(hB, fc2_w, fc2_b, (float*)d_out, n);
}

// Round 4
// 1004.951 us; speedup vs baseline: 1.3992x; 1.3992x over previous
//
#include <hip/hip_runtime.h>
#include <math.h>

// GAT forward. R3: fp16 MFMA GEMMs + fp16 edge-phase operands (R2 was bf16;
// absmax 0.227 = pure precision failure, layout verified. fp16 gives 8x
// tighter rounding at same speed/bytes).
// Structure: CSR build -> W pack (fp16 frag-major) -> fc0 (fp32) ->
//   2x [ gemm_mfma(k,q,v->fp16; ws->fp32) -> fused edge (fp16 gathers, fp32 math) ]
//   -> fc1 (mfma, gelu, fp16 out) -> fc2 (wave reduce).

typedef _Float16 f16x8 __attribute__((ext_vector_type(8)));
typedef float f32x4 __attribute__((ext_vector_type(4)));

__device__ __forceinline__ ushort f2h(float x) {
    union { _Float16 h; ushort u; } v;
    v.h = (_Float16)x;
    return v.u;
}
__device__ __forceinline__ float h2f(ushort u) {
    union { ushort u; _Float16 h; } v;
    v.u = u;
    return (float)v.h;
}

__device__ __forceinline__ float gelu_f(float x) {
    float x3 = x * x * x;
    return 0.5f * x * (1.f + tanhf(0.7978845608028654f * (x + 0.044715f * x3)));
}

// ---------------- CSR build ----------------
__global__ void k_zero(int* __restrict__ p, int n) {
    int i = blockIdx.x * blockDim.x + threadIdx.x;
    if (i < n) p[i] = 0;
}

__global__ void k_hist(const int* __restrict__ dst, int* __restrict__ deg, int e) {
    int i = blockIdx.x * blockDim.x + threadIdx.x;
    if (i < e) atomicAdd(&deg[dst[i]], 1);
}

__global__ void k_scan(const int* __restrict__ deg, int* __restrict__ rowp,
                       int* __restrict__ cur, int n, int e) {
    __shared__ int sums[1024];
    int t = threadIdx.x;
    int chunk = (n + 1023) >> 10;
    int beg = t * chunk;
    int end = min(beg + chunk, n);
    int s = 0;
    for (int i = beg; i < end; ++i) s += deg[i];
    sums[t] = s;
    __syncthreads();
    for (int off = 1; off < 1024; off <<= 1) {
        int v = (t >= off) ? sums[t - off] : 0;
        __syncthreads();
        sums[t] += v;
        __syncthreads();
    }
    int run = sums[t] - s;
    for (int i = beg; i < end; ++i) {
        rowp[i] = run;
        cur[i] = run;
        run += deg[i];
    }
    if (t == 0) rowp[n] = e;
}

__global__ void k_scatter(const int* __restrict__ src, const int* __restrict__ dst,
                          int* __restrict__ cur, int* __restrict__ csrc, int e) {
    int i = blockIdx.x * blockDim.x + threadIdx.x;
    if (i < e) {
        int p = atomicAdd(&cur[dst[i]], 1);
        csrc[p] = src[i];
    }
}

// ---------------- W pack: fp32 [128][128] -> fp16 frag-major ----------------
// Wp[id][kc][nf][l][j] = W[kc*32 + (l>>4)*8 + j][nf*16 + (l&15)]
__global__ void k_pack(const float* __restrict__ Wk, const float* __restrict__ Wq,
                       const float* __restrict__ Wv, const float* __restrict__ Ws,
                       const float* __restrict__ Wfc1, ushort* __restrict__ Wp) {
    int id = blockIdx.y;  // 0..8: {k,q,v,ws}L0, {k,q,v,ws}L1, fc1
    const float* src;
    if (id < 8) {
        int m = id & 3, layer = id >> 2;
        src = (m == 0) ? Wk : (m == 1) ? Wq : (m == 2) ? Wv : Ws;
        src += layer * 16384;
    } else {
        src = Wfc1;
    }
    int o = blockIdx.x * 256 + threadIdx.x;  // 0..16383
    int j = o & 7, l = (o >> 3) & 63, nf = (o >> 9) & 7, kc = o >> 12;
    int row = kc * 32 + ((l >> 4) << 3) + j;
    int col = nf * 16 + (l & 15);
    Wp[id * 16384 + o] = f2h(src[row * 128 + col]);
}

// ---------------- fc0: [N,16] @ [16,128] + b (fp32) ----------------
__global__ __launch_bounds__(256) void k_fc0(const float* __restrict__ X,
                                             const float* __restrict__ W,
                                             const float* __restrict__ b,
                                             float* __restrict__ H, int n) {
    __shared__ float Ws[16 * 128];
    __shared__ float xs[2][16];
    int t = threadIdx.x;
#pragma unroll
    for (int i = 0; i < 8; ++i) Ws[t + i * 256] = W[t + i * 256];
    if (t < 32) {
        int nn = blockIdx.x * 2 + (t >> 4);
        xs[t >> 4][t & 15] = (nn < n) ? X[nn * 16 + (t & 15)] : 0.f;
    }
    __syncthreads();
    int nd = blockIdx.x * 2 + (t >> 7);
    if (nd < n) {
        int c = t & 127;
        float acc = b[c];
#pragma unroll
        for (int j = 0; j < 16; ++j) acc += xs[t >> 7][j] * Ws[j * 128 + c];
        H[nd * 128 + c] = acc;
    }
}

// ---------------- MFMA GEMM: [N,128] @ [128,128] x nmat ----------------
// block 256 (4 waves) computes 64 rows for ALL nmat matrices (A staged once).
// A: fp32 global -> fp16 LDS tile [64][128], XOR-swizzled (byte ^= (row&7)<<4).
// B: packed frag-major fp16 (k_pack). acc fp32; epilogue bias (+gelu) ->
// fp32 or fp16 output per flags (bit m: fp16 out; bit 8+m: gelu).
__global__ __launch_bounds__(256) void k_gemm_mfma(
    const float* __restrict__ A, int n, const ushort* __restrict__ Wp,
    const float* __restrict__ b0, void* __restrict__ o0,
    const float* __restrict__ b1, void* __restrict__ o1,
    const float* __restrict__ b2, void* __restrict__ o2,
    const float* __restrict__ b3, void* __restrict__ o3,
    int flags, int nmat) {
    __shared__ ushort As[64 * 128];  // 16 KB
    char* Asb = (char*)As;
    int t = threadIdx.x;
    int rbase = blockIdx.x * 64;

    // stage A tile fp32 -> fp16, swizzled
#pragma unroll
    for (int i = 0; i < 8; ++i) {
        int f = t * 4 + i * 1024;  // element index
        int r = f >> 7, c = f & 127;
        float4 v = {0.f, 0.f, 0.f, 0.f};
        if (rbase + r < n) v = *(const float4*)&A[(size_t)(rbase + r) * 128 + c];
        ushort4 u;
        u.x = f2h(v.x); u.y = f2h(v.y); u.z = f2h(v.z); u.w = f2h(v.w);
        int byte = (r * 256 + c * 2) ^ ((r & 7) << 4);
        *(ushort4*)(Asb + byte) = u;
    }
    __syncthreads();

    int w = t >> 6, l = t & 63;
    int arow = w * 16 + (l & 15);   // tile row this lane's A frag comes from
    int kq = l >> 4;                // k-quadrant 0..3

    // A frags for all 4 k-chunks (reused across mats)
    f16x8 a[4];
#pragma unroll
    for (int kc = 0; kc < 4; ++kc) {
        int byte = (arow * 256 + kc * 64 + kq * 16) ^ ((arow & 7) << 4);
        a[kc] = *(const f16x8*)(Asb + byte);
    }

    for (int m = 0; m < nmat; ++m) {
        const float* bias; void* op;
        if (m == 0)      { bias = b0; op = o0; }
        else if (m == 1) { bias = b1; op = o1; }
        else if (m == 2) { bias = b2; op = o2; }
        else             { bias = b3; op = o3; }
        int isf16 = (flags >> m) & 1;
        int act   = (flags >> (8 + m)) & 1;
        const ushort* wb = Wp + m * 16384;

        f32x4 acc[8];
#pragma unroll
        for (int nf = 0; nf < 8; ++nf) acc[nf] = (f32x4){0.f, 0.f, 0.f, 0.f};

#pragma unroll
        for (int kc = 0; kc < 4; ++kc) {
#pragma unroll
            for (int nf = 0; nf < 8; ++nf) {
                f16x8 b = *(const f16x8*)(wb + (((kc * 8 + nf) * 64 + l) << 3));
                acc[nf] = __builtin_amdgcn_mfma_f32_16x16x32_f16(a[kc], b, acc[nf], 0, 0, 0);
            }
        }

        // epilogue: D row=(l>>4)*4+r, col=l&15 within each 16x16 frag
#pragma unroll
        for (int nf = 0; nf < 8; ++nf) {
            int col = nf * 16 + (l & 15);
            float bia = bias[col];
#pragma unroll
            for (int r = 0; r < 4; ++r) {
                int row = rbase + w * 16 + (l >> 4) * 4 + r;
                if (row < n) {
                    float o = acc[nf][r] + bia;
                    if (act) o = gelu_f(o);
                    if (isf16) ((ushort*)op)[(size_t)row * 128 + col] = f2h(o);
                    else       ((float*)op)[(size_t)row * 128 + col] = o;
                }
            }
        }
    }
}

// ---------------- fused edge phase (fp16 K/Q/V), one wave per dst node ----------------
__global__ void k_edge_hf(const ushort* __restrict__ K, const ushort* __restrict__ Q,
                          const ushort* __restrict__ V, const int* __restrict__ rowp,
                          const int* __restrict__ csrc, float* __restrict__ H, int n,
                          int act) {
    int wid = (int)((blockIdx.x * blockDim.x + threadIdx.x) >> 6);
    int lane = threadIdx.x & 63;
    if (wid >= n) return;
    int e0 = rowp[wid], e1 = rowp[wid + 1];
    unsigned qraw = *(const unsigned*)(Q + (size_t)wid * 128 + lane * 2);
    float qx = h2f((ushort)(qraw & 0xffff)), qy = h2f((ushort)(qraw >> 16));
    float m = -INFINITY;
    float denom = 0.f;
    float accx = 0.f, accy = 0.f;
    for (int eb = e0; eb < e1; eb += 64) {
        int cnt = min(64, e1 - eb);
        int sl = (eb + lane < e1) ? csrc[eb + lane] : 0;
        for (int j = 0; j < cnt; ++j) {
            int s = __shfl(sl, j);
            unsigned kraw = *(const unsigned*)(K + (size_t)s * 128 + lane * 2);
            float sc = h2f((ushort)(kraw & 0xffff)) * qx + h2f((ushort)(kraw >> 16)) * qy;
            sc += __shfl_xor(sc, 1);
            sc += __shfl_xor(sc, 2);
            sc += __shfl_xor(sc, 4);
            sc += __shfl_xor(sc, 8);
            sc += __shfl_xor(sc, 16);
            unsigned vraw = *(const unsigned*)(V + (size_t)s * 128 + lane * 2);
            float vx = h2f((ushort)(vraw & 0xffff)), vy = h2f((ushort)(vraw >> 16));
            if (sc > m) {
                float scale = __expf(m - sc);
                denom = denom * scale + 1.f;
                accx = accx * scale + vx;
                accy = accy * scale + vy;
                m = sc;
            } else {
                float p = __expf(sc - m);
                denom += p;
                accx += p * vx;
                accy += p * vy;
            }
        }
    }
    float inv = (denom > 0.f) ? 1.f / denom : 0.f;
    float2 s2 = *(float2*)&H[(size_t)wid * 128 + lane * 2];
    float ox = s2.x + accx * inv;
    float oy = s2.y + accy * inv;
    if (act) {
        ox = gelu_f(ox);
        oy = gelu_f(oy);
    }
    float2 o = {ox, oy};
    *(float2*)&H[(size_t)wid * 128 + lane * 2] = o;
}

// ---------------- fc2: fp16 [N,128] @ fp32 [128,4] + b ----------------
__global__ void k_fc2(const ushort* __restrict__ Hh, const float* __restrict__ W,
                      const float* __restrict__ b, float* __restrict__ out, int n) {
    int wid = (int)((blockIdx.x * blockDim.x + threadIdx.x) >> 6);
    int lane = threadIdx.x & 63;
    if (wid >= n) return;
    unsigned raw = *(const unsigned*)(Hh + (size_t)wid * 128 + lane * 2);
    float x0 = h2f((ushort)(raw & 0xffff)), x1 = h2f((ushort)(raw >> 16));
    float4 wA = *(const float4*)&W[(lane * 2) * 4];
    float4 wB = *(const float4*)&W[(lane * 2 + 1) * 4];
    float a0 = x0 * wA.x + x1 * wB.x;
    float a1 = x0 * wA.y + x1 * wB.y;
    float a2 = x0 * wA.z + x1 * wB.z;
    float a3 = x0 * wA.w + x1 * wB.w;
#pragma unroll
    for (int off = 1; off < 64; off <<= 1) {
        a0 += __shfl_xor(a0, off);
        a1 += __shfl_xor(a1, off);
        a2 += __shfl_xor(a2, off);
        a3 += __shfl_xor(a3, off);
    }
    if (lane < 4) {
        float v = (lane == 0) ? a0 : (lane == 1) ? a1 : (lane == 2) ? a2 : a3;
        out[(size_t)wid * 4 + lane] = v + b[lane];
    }
}

extern "C" void kernel_launch(void* const* d_in, const int* in_sizes, int n_in,
                              void* d_out, int out_size, void* d_ws, size_t ws_size,
                              hipStream_t stream) {
    const float* x     = (const float*)d_in[0];
    const int*   src   = (const int*)d_in[1];
    const int*   dst   = (const int*)d_in[2];
    const float* fc0_w = (const float*)d_in[3];
    const float* fc0_b = (const float*)d_in[4];
    const float* Wk    = (const float*)d_in[5];
    const float* bk    = (const float*)d_in[6];
    const float* Wq    = (const float*)d_in[7];
    const float* bq    = (const float*)d_in[8];
    const float* Wv    = (const float*)d_in[9];
    const float* bv    = (const float*)d_in[10];
    const float* ws_w  = (const float*)d_in[11];
    const float* ws_b  = (const float*)d_in[12];
    const float* fc1_w = (const float*)d_in[13];
    const float* fc1_b = (const float*)d_in[14];
    const float* fc2_w = (const float*)d_in[15];
    const float* fc2_b = (const float*)d_in[16];

    int n = in_sizes[0] / 16;
    int e = in_sizes[1];

    float*  hA  = (float*)d_ws;
    float*  hB  = hA + (size_t)n * 128;
    ushort* Kb  = (ushort*)(hB + (size_t)n * 128);
    ushort* Qb  = Kb + (size_t)n * 128;
    ushort* Vb  = Qb + (size_t)n * 128;
    ushort* Wp  = Vb + (size_t)n * 128;   // 9 * 16384 fp16
    int* deg    = (int*)(Wp + 9 * 16384);
    int* rowp   = deg + n;
    int* cur    = rowp + n + 1;
    int* csrc   = cur + n;

    // CSR build
    k_zero<<<(n + 255) / 256, 256, 0, stream>>>(deg, n);
    k_hist<<<(e + 255) / 256, 256, 0, stream>>>(dst, deg, e);
    k_scan<<<1, 1024, 0, stream>>>(deg, rowp, cur, n, e);
    k_scatter<<<(e + 255) / 256, 256, 0, stream>>>(src, dst, cur, csrc, e);

    // pack all 9 weight matrices to fp16 frag-major
    k_pack<<<dim3(64, 9), 256, 0, stream>>>(Wk, Wq, Wv, ws_w, fc1_w, Wp);

    // fc0 (fp32)
    k_fc0<<<(n + 1) / 2, 256, 0, stream>>>(x, fc0_w, fc0_b, hA, n);

    int gx = (n + 63) / 64;
    // layer 0: k,q,v -> fp16; ws -> fp32 into hB. Then edge (+gelu).
    k_gemm_mfma<<<gx, 256, 0, stream>>>(hA, n, Wp, bk, Kb, bq, Qb, bv, Vb, ws_b, hB,
                                        0x07, 4);
    k_edge_hf<<<(n + 3) / 4, 256, 0, stream>>>(Kb, Qb, Vb, rowp, csrc, hB, n, 1);
    // layer 1
    k_gemm_mfma<<<gx, 256, 0, stream>>>(hB, n, Wp + 4 * 16384, bk + 128, Kb, bq + 128,
                                        Qb, bv + 128, Vb, ws_b + 128, hA, 0x07, 4);
    k_edge_hf<<<(n + 3) / 4, 256, 0, stream>>>(Kb, Qb, Vb, rowp, csrc, hA, n, 0);

    // fc1 + gelu -> fp16 (reuse Kb)
    k_gemm_mfma<<<gx, 256, 0, stream>>>(hA, n, Wp + 8 * 16384, fc1_b, Kb, fc1_b, Kb,
                                        fc1_b, Kb, fc1_b, Kb, 0x101, 1);
    // fc2
    k_fc2<<<(n + 3) / 4, 256, 0, stream>>>(Kb, fc2_w, fc2_b, (float*)d_out, n);
}

// Round 5
// 785.825 us; speedup vs baseline: 1.7893x; 1.2788x over previous
//
#include <hip/hip_runtime.h>
#include <math.h>

// GAT forward. R4: replace single-block k_scan (229us, 0.15% occupancy,
// latency-serialized) with 3-kernel parallel prefix scan (~15us).
// Structure: CSR build (hist -> part/scanb/add -> scatter) -> W pack (fp16
// frag-major) -> fc0 (fp32) -> 2x [ gemm_mfma(k,q,v->fp16; ws->fp32) ->
// fused edge (fp16 gathers, fp32 math) ] -> fc1 (mfma+gelu, fp16) -> fc2.

typedef _Float16 f16x8 __attribute__((ext_vector_type(8)));
typedef float f32x4 __attribute__((ext_vector_type(4)));

__device__ __forceinline__ ushort f2h(float x) {
    union { _Float16 h; ushort u; } v;
    v.h = (_Float16)x;
    return v.u;
}
__device__ __forceinline__ float h2f(ushort u) {
    union { ushort u; _Float16 h; } v;
    v.u = u;
    return (float)v.h;
}

__device__ __forceinline__ float gelu_f(float x) {
    float x3 = x * x * x;
    return 0.5f * x * (1.f + tanhf(0.7978845608028654f * (x + 0.044715f * x3)));
}

// ---------------- CSR build ----------------
__global__ void k_zero(int* __restrict__ p, int n) {
    int i = blockIdx.x * blockDim.x + threadIdx.x;
    if (i < n) p[i] = 0;
}

__global__ void k_hist(const int* __restrict__ dst, int* __restrict__ deg, int e) {
    int i = blockIdx.x * blockDim.x + threadIdx.x;
    if (i < e) atomicAdd(&deg[dst[i]], 1);
}

// parallel exclusive scan, step 1: per-block (1024 elems) prefix + block sum.
// pre (=rowp scratch) gets in-block exclusive prefix per element.
__global__ __launch_bounds__(256) void k_part(const int* __restrict__ deg,
                                              int* __restrict__ pre,
                                              int* __restrict__ bsum, int n) {
    __shared__ int lds[256];
    int t = threadIdx.x;
    int base = blockIdx.x * 1024 + t * 4;
    int d0 = 0, d1 = 0, d2 = 0, d3 = 0;
    if (base + 3 < n) {
        int4 d = *(const int4*)&deg[base];
        d0 = d.x; d1 = d.y; d2 = d.z; d3 = d.w;
    } else {
        if (base + 0 < n) d0 = deg[base + 0];
        if (base + 1 < n) d1 = deg[base + 1];
        if (base + 2 < n) d2 = deg[base + 2];
        if (base + 3 < n) d3 = deg[base + 3];
    }
    int s0 = d0, s1 = s0 + d1, s2 = s1 + d2, s3 = s2 + d3;  // inclusive in quad
    lds[t] = s3;
    __syncthreads();
    for (int off = 1; off < 256; off <<= 1) {
        int v = (t >= off) ? lds[t - off] : 0;
        __syncthreads();
        lds[t] += v;
        __syncthreads();
    }
    int excl = lds[t] - s3;  // exclusive prefix of this quad within block
    if (base + 0 < n) pre[base + 0] = excl;
    if (base + 1 < n) pre[base + 1] = excl + s0;
    if (base + 2 < n) pre[base + 2] = excl + s1;
    if (base + 3 < n) pre[base + 3] = excl + s2;
    if (t == 255) bsum[blockIdx.x] = lds[255];
}

// step 2: exclusive scan of block sums (nb <= 128), in place.
__global__ void k_scanb(int* __restrict__ bsum, int nb) {
    __shared__ int lds[128];
    int t = threadIdx.x;
    int v = (t < nb) ? bsum[t] : 0;
    lds[t] = v;
    __syncthreads();
    for (int off = 1; off < 128; off <<= 1) {
        int u = (t >= off) ? lds[t - off] : 0;
        __syncthreads();
        lds[t] += u;
        __syncthreads();
    }
    if (t < nb) bsum[t] = lds[t] - v;
}

// step 3: add block offsets -> final rowp; init cur; set rowp[n]=e.
__global__ __launch_bounds__(256) void k_add(int* __restrict__ rowp,
                                             int* __restrict__ cur,
                                             const int* __restrict__ bsum, int n,
                                             int e) {
    int t = threadIdx.x;
    int base = blockIdx.x * 1024 + t * 4;
    int off = bsum[blockIdx.x];
#pragma unroll
    for (int j = 0; j < 4; ++j) {
        int i = base + j;
        if (i < n) {
            int v = rowp[i] + off;
            rowp[i] = v;
            cur[i] = v;
        }
    }
    if (blockIdx.x == 0 && t == 0) rowp[n] = e;
}

__global__ void k_scatter(const int* __restrict__ src, const int* __restrict__ dst,
                          int* __restrict__ cur, int* __restrict__ csrc, int e) {
    int i = blockIdx.x * blockDim.x + threadIdx.x;
    if (i < e) {
        int p = atomicAdd(&cur[dst[i]], 1);
        csrc[p] = src[i];
    }
}

// ---------------- W pack: fp32 [128][128] -> fp16 frag-major ----------------
// Wp[id][kc][nf][l][j] = W[kc*32 + (l>>4)*8 + j][nf*16 + (l&15)]
__global__ void k_pack(const float* __restrict__ Wk, const float* __restrict__ Wq,
                       const float* __restrict__ Wv, const float* __restrict__ Ws,
                       const float* __restrict__ Wfc1, ushort* __restrict__ Wp) {
    int id = blockIdx.y;  // 0..8: {k,q,v,ws}L0, {k,q,v,ws}L1, fc1
    const float* src;
    if (id < 8) {
        int m = id & 3, layer = id >> 2;
        src = (m == 0) ? Wk : (m == 1) ? Wq : (m == 2) ? Wv : Ws;
        src += layer * 16384;
    } else {
        src = Wfc1;
    }
    int o = blockIdx.x * 256 + threadIdx.x;  // 0..16383
    int j = o & 7, l = (o >> 3) & 63, nf = (o >> 9) & 7, kc = o >> 12;
    int row = kc * 32 + ((l >> 4) << 3) + j;
    int col = nf * 16 + (l & 15);
    Wp[id * 16384 + o] = f2h(src[row * 128 + col]);
}

// ---------------- fc0: [N,16] @ [16,128] + b (fp32) ----------------
__global__ __launch_bounds__(256) void k_fc0(const float* __restrict__ X,
                                             const float* __restrict__ W,
                                             const float* __restrict__ b,
                                             float* __restrict__ H, int n) {
    __shared__ float Ws[16 * 128];
    __shared__ float xs[2][16];
    int t = threadIdx.x;
#pragma unroll
    for (int i = 0; i < 8; ++i) Ws[t + i * 256] = W[t + i * 256];
    if (t < 32) {
        int nn = blockIdx.x * 2 + (t >> 4);
        xs[t >> 4][t & 15] = (nn < n) ? X[nn * 16 + (t & 15)] : 0.f;
    }
    __syncthreads();
    int nd = blockIdx.x * 2 + (t >> 7);
    if (nd < n) {
        int c = t & 127;
        float acc = b[c];
#pragma unroll
        for (int j = 0; j < 16; ++j) acc += xs[t >> 7][j] * Ws[j * 128 + c];
        H[nd * 128 + c] = acc;
    }
}

// ---------------- MFMA GEMM: [N,128] @ [128,128] x nmat ----------------
__global__ __launch_bounds__(256) void k_gemm_mfma(
    const float* __restrict__ A, int n, const ushort* __restrict__ Wp,
    const float* __restrict__ b0, void* __restrict__ o0,
    const float* __restrict__ b1, void* __restrict__ o1,
    const float* __restrict__ b2, void* __restrict__ o2,
    const float* __restrict__ b3, void* __restrict__ o3,
    int flags, int nmat) {
    __shared__ ushort As[64 * 128];  // 16 KB
    char* Asb = (char*)As;
    int t = threadIdx.x;
    int rbase = blockIdx.x * 64;

    // stage A tile fp32 -> fp16, swizzled (byte ^= (row&7)<<4)
#pragma unroll
    for (int i = 0; i < 8; ++i) {
        int f = t * 4 + i * 1024;  // element index
        int r = f >> 7, c = f & 127;
        float4 v = {0.f, 0.f, 0.f, 0.f};
        if (rbase + r < n) v = *(const float4*)&A[(size_t)(rbase + r) * 128 + c];
        ushort4 u;
        u.x = f2h(v.x); u.y = f2h(v.y); u.z = f2h(v.z); u.w = f2h(v.w);
        int byte = (r * 256 + c * 2) ^ ((r & 7) << 4);
        *(ushort4*)(Asb + byte) = u;
    }
    __syncthreads();

    int w = t >> 6, l = t & 63;
    int arow = w * 16 + (l & 15);
    int kq = l >> 4;

    f16x8 a[4];
#pragma unroll
    for (int kc = 0; kc < 4; ++kc) {
        int byte = (arow * 256 + kc * 64 + kq * 16) ^ ((arow & 7) << 4);
        a[kc] = *(const f16x8*)(Asb + byte);
    }

    for (int m = 0; m < nmat; ++m) {
        const float* bias; void* op;
        if (m == 0)      { bias = b0; op = o0; }
        else if (m == 1) { bias = b1; op = o1; }
        else if (m == 2) { bias = b2; op = o2; }
        else             { bias = b3; op = o3; }
        int isf16 = (flags >> m) & 1;
        int act   = (flags >> (8 + m)) & 1;
        const ushort* wb = Wp + m * 16384;

        f32x4 acc[8];
#pragma unroll
        for (int nf = 0; nf < 8; ++nf) acc[nf] = (f32x4){0.f, 0.f, 0.f, 0.f};

#pragma unroll
        for (int kc = 0; kc < 4; ++kc) {
#pragma unroll
            for (int nf = 0; nf < 8; ++nf) {
                f16x8 b = *(const f16x8*)(wb + (((kc * 8 + nf) * 64 + l) << 3));
                acc[nf] = __builtin_amdgcn_mfma_f32_16x16x32_f16(a[kc], b, acc[nf], 0, 0, 0);
            }
        }

#pragma unroll
        for (int nf = 0; nf < 8; ++nf) {
            int col = nf * 16 + (l & 15);
            float bia = bias[col];
#pragma unroll
            for (int r = 0; r < 4; ++r) {
                int row = rbase + w * 16 + (l >> 4) * 4 + r;
                if (row < n) {
                    float o = acc[nf][r] + bia;
                    if (act) o = gelu_f(o);
                    if (isf16) ((ushort*)op)[(size_t)row * 128 + col] = f2h(o);
                    else       ((float*)op)[(size_t)row * 128 + col] = o;
                }
            }
        }
    }
}

// ---------------- fused edge phase (fp16 K/Q/V), one wave per dst node ----------------
__global__ void k_edge_hf(const ushort* __restrict__ K, const ushort* __restrict__ Q,
                          const ushort* __restrict__ V, const int* __restrict__ rowp,
                          const int* __restrict__ csrc, float* __restrict__ H, int n,
                          int act) {
    int wid = (int)((blockIdx.x * blockDim.x + threadIdx.x) >> 6);
    int lane = threadIdx.x & 63;
    if (wid >= n) return;
    int e0 = rowp[wid], e1 = rowp[wid + 1];
    unsigned qraw = *(const unsigned*)(Q + (size_t)wid * 128 + lane * 2);
    float qx = h2f((ushort)(qraw & 0xffff)), qy = h2f((ushort)(qraw >> 16));
    float m = -INFINITY;
    float denom = 0.f;
    float accx = 0.f, accy = 0.f;
    for (int eb = e0; eb < e1; eb += 64) {
        int cnt = min(64, e1 - eb);
        int sl = (eb + lane < e1) ? csrc[eb + lane] : 0;
        for (int j = 0; j < cnt; ++j) {
            int s = __shfl(sl, j);
            unsigned kraw = *(const unsigned*)(K + (size_t)s * 128 + lane * 2);
            float sc = h2f((ushort)(kraw & 0xffff)) * qx + h2f((ushort)(kraw >> 16)) * qy;
            sc += __shfl_xor(sc, 1);
            sc += __shfl_xor(sc, 2);
            sc += __shfl_xor(sc, 4);
            sc += __shfl_xor(sc, 8);
            sc += __shfl_xor(sc, 16);
            unsigned vraw = *(const unsigned*)(V + (size_t)s * 128 + lane * 2);
            float vx = h2f((ushort)(vraw & 0xffff)), vy = h2f((ushort)(vraw >> 16));
            if (sc > m) {
                float scale = __expf(m - sc);
                denom = denom * scale + 1.f;
                accx = accx * scale + vx;
                accy = accy * scale + vy;
                m = sc;
            } else {
                float p = __expf(sc - m);
                denom += p;
                accx += p * vx;
                accy += p * vy;
            }
        }
    }
    float inv = (denom > 0.f) ? 1.f / denom : 0.f;
    float2 s2 = *(float2*)&H[(size_t)wid * 128 + lane * 2];
    float ox = s2.x + accx * inv;
    float oy = s2.y + accy * inv;
    if (act) {
        ox = gelu_f(ox);
        oy = gelu_f(oy);
    }
    float2 o = {ox, oy};
    *(float2*)&H[(size_t)wid * 128 + lane * 2] = o;
}

// ---------------- fc2: fp16 [N,128] @ fp32 [128,4] + b ----------------
__global__ void k_fc2(const ushort* __restrict__ Hh, const float* __restrict__ W,
                      const float* __restrict__ b, float* __restrict__ out, int n) {
    int wid = (int)((blockIdx.x * blockDim.x + threadIdx.x) >> 6);
    int lane = threadIdx.x & 63;
    if (wid >= n) return;
    unsigned raw = *(const unsigned*)(Hh + (size_t)wid * 128 + lane * 2);
    float x0 = h2f((ushort)(raw & 0xffff)), x1 = h2f((ushort)(raw >> 16));
    float4 wA = *(const float4*)&W[(lane * 2) * 4];
    float4 wB = *(const float4*)&W[(lane * 2 + 1) * 4];
    float a0 = x0 * wA.x + x1 * wB.x;
    float a1 = x0 * wA.y + x1 * wB.y;
    float a2 = x0 * wA.z + x1 * wB.z;
    float a3 = x0 * wA.w + x1 * wB.w;
#pragma unroll
    for (int off = 1; off < 64; off <<= 1) {
        a0 += __shfl_xor(a0, off);
        a1 += __shfl_xor(a1, off);
        a2 += __shfl_xor(a2, off);
        a3 += __shfl_xor(a3, off);
    }
    if (lane < 4) {
        float v = (lane == 0) ? a0 : (lane == 1) ? a1 : (lane == 2) ? a2 : a3;
        out[(size_t)wid * 4 + lane] = v + b[lane];
    }
}

extern "C" void kernel_launch(void* const* d_in, const int* in_sizes, int n_in,
                              void* d_out, int out_size, void* d_ws, size_t ws_size,
                              hipStream_t stream) {
    const float* x     = (const float*)d_in[0];
    const int*   src   = (const int*)d_in[1];
    const int*   dst   = (const int*)d_in[2];
    const float* fc0_w = (const float*)d_in[3];
    const float* fc0_b = (const float*)d_in[4];
    const float* Wk    = (const float*)d_in[5];
    const float* bk    = (const float*)d_in[6];
    const float* Wq    = (const float*)d_in[7];
    const float* bq    = (const float*)d_in[8];
    const float* Wv    = (const float*)d_in[9];
    const float* bv    = (const float*)d_in[10];
    const float* ws_w  = (const float*)d_in[11];
    const float* ws_b  = (const float*)d_in[12];
    const float* fc1_w = (const float*)d_in[13];
    const float* fc1_b = (const float*)d_in[14];
    const float* fc2_w = (const float*)d_in[15];
    const float* fc2_b = (const float*)d_in[16];

    int n = in_sizes[0] / 16;
    int e = in_sizes[1];

    float*  hA  = (float*)d_ws;
    float*  hB  = hA + (size_t)n * 128;
    ushort* Kb  = (ushort*)(hB + (size_t)n * 128);
    ushort* Qb  = Kb + (size_t)n * 128;
    ushort* Vb  = Qb + (size_t)n * 128;
    ushort* Wp  = Vb + (size_t)n * 128;   // 9 * 16384 fp16
    int* deg    = (int*)(Wp + 9 * 16384);
    int* rowp   = deg + n;
    int* cur    = rowp + n + 1;
    int* csrc   = cur + n;
    int* bsum   = csrc + e;               // 128 ints scratch

    int nb = (n + 1023) / 1024;           // blocks for the scan (<=128 supported)

    // CSR build
    k_zero<<<(n + 255) / 256, 256, 0, stream>>>(deg, n);
    k_hist<<<(e + 255) / 256, 256, 0, stream>>>(dst, deg, e);
    k_part<<<nb, 256, 0, stream>>>(deg, rowp, bsum, n);
    k_scanb<<<1, 128, 0, stream>>>(bsum, nb);
    k_add<<<nb, 256, 0, stream>>>(rowp, cur, bsum, n, e);
    k_scatter<<<(e + 255) / 256, 256, 0, stream>>>(src, dst, cur, csrc, e);

    // pack all 9 weight matrices to fp16 frag-major
    k_pack<<<dim3(64, 9), 256, 0, stream>>>(Wk, Wq, Wv, ws_w, fc1_w, Wp);

    // fc0 (fp32)
    k_fc0<<<(n + 1) / 2, 256, 0, stream>>>(x, fc0_w, fc0_b, hA, n);

    int gx = (n + 63) / 64;
    // layer 0: k,q,v -> fp16; ws -> fp32 into hB. Then edge (+gelu).
    k_gemm_mfma<<<gx, 256, 0, stream>>>(hA, n, Wp, bk, Kb, bq, Qb, bv, Vb, ws_b, hB,
                                        0x07, 4);
    k_edge_hf<<<(n + 3) / 4, 256, 0, stream>>>(Kb, Qb, Vb, rowp, csrc, hB, n, 1);
    // layer 1
    k_gemm_mfma<<<gx, 256, 0, stream>>>(hB, n, Wp + 4 * 16384, bk + 128, Kb, bq + 128,
                                        Qb, bv + 128, Vb, ws_b + 128, hA, 0x07, 4);
    k_edge_hf<<<(n + 3) / 4, 256, 0, stream>>>(Kb, Qb, Vb, rowp, csrc, hA, n, 0);

    // fc1 + gelu -> fp16 (reuse Kb)
    k_gemm_mfma<<<gx, 256, 0, stream>>>(hA, n, Wp + 8 * 16384, fc1_b, Kb, fc1_b, Kb,
                                        fc1_b, Kb, fc1_b, Kb, 0x101, 1);
    // fc2
    k_fc2<<<(n + 3) / 4, 256, 0, stream>>>(Kb, fc2_w, fc2_b, (float*)d_out, n);
}

// Round 6
// 700.287 us; speedup vs baseline: 2.0079x; 1.1221x over previous
//
#include <hip/hip_runtime.h>
#include <math.h>

// GAT forward. R5: edge kernel restructured — 2 edges per wave (4 feats/lane,
// half-wave per edge, interleaved), 4-shfl head reduce, branchless online
// softmax, end-merge via shfl_xor(32). R4 edge was VALU-bound (55% VALUBusy,
// 33% HBM) at ~20 ops/edge/lane; this cuts VALU per edge ~2.5x.
// Structure: CSR build (hist -> part/scanb/add -> scatter) -> W pack (fp16
// frag-major) -> fc0 (fp32) -> 2x [ gemm_mfma(k,q,v->fp16; ws->fp32) ->
// fused edge ] -> fc1 (mfma+gelu, fp16) -> fc2.

typedef _Float16 f16x8 __attribute__((ext_vector_type(8)));
typedef float f32x4 __attribute__((ext_vector_type(4)));

__device__ __forceinline__ ushort f2h(float x) {
    union { _Float16 h; ushort u; } v;
    v.h = (_Float16)x;
    return v.u;
}
__device__ __forceinline__ float h2f(ushort u) {
    union { ushort u; _Float16 h; } v;
    v.u = u;
    return (float)v.h;
}

__device__ __forceinline__ float gelu_f(float x) {
    float x3 = x * x * x;
    return 0.5f * x * (1.f + tanhf(0.7978845608028654f * (x + 0.044715f * x3)));
}

// ---------------- CSR build ----------------
__global__ void k_zero(int* __restrict__ p, int n) {
    int i = blockIdx.x * blockDim.x + threadIdx.x;
    if (i < n) p[i] = 0;
}

__global__ void k_hist(const int* __restrict__ dst, int* __restrict__ deg, int e) {
    int i = blockIdx.x * blockDim.x + threadIdx.x;
    if (i < e) atomicAdd(&deg[dst[i]], 1);
}

__global__ __launch_bounds__(256) void k_part(const int* __restrict__ deg,
                                              int* __restrict__ pre,
                                              int* __restrict__ bsum, int n) {
    __shared__ int lds[256];
    int t = threadIdx.x;
    int base = blockIdx.x * 1024 + t * 4;
    int d0 = 0, d1 = 0, d2 = 0, d3 = 0;
    if (base + 3 < n) {
        int4 d = *(const int4*)&deg[base];
        d0 = d.x; d1 = d.y; d2 = d.z; d3 = d.w;
    } else {
        if (base + 0 < n) d0 = deg[base + 0];
        if (base + 1 < n) d1 = deg[base + 1];
        if (base + 2 < n) d2 = deg[base + 2];
        if (base + 3 < n) d3 = deg[base + 3];
    }
    int s0 = d0, s1 = s0 + d1, s2 = s1 + d2, s3 = s2 + d3;
    lds[t] = s3;
    __syncthreads();
    for (int off = 1; off < 256; off <<= 1) {
        int v = (t >= off) ? lds[t - off] : 0;
        __syncthreads();
        lds[t] += v;
        __syncthreads();
    }
    int excl = lds[t] - s3;
    if (base + 0 < n) pre[base + 0] = excl;
    if (base + 1 < n) pre[base + 1] = excl + s0;
    if (base + 2 < n) pre[base + 2] = excl + s1;
    if (base + 3 < n) pre[base + 3] = excl + s2;
    if (t == 255) bsum[blockIdx.x] = lds[255];
}

__global__ void k_scanb(int* __restrict__ bsum, int nb) {
    __shared__ int lds[128];
    int t = threadIdx.x;
    int v = (t < nb) ? bsum[t] : 0;
    lds[t] = v;
    __syncthreads();
    for (int off = 1; off < 128; off <<= 1) {
        int u = (t >= off) ? lds[t - off] : 0;
        __syncthreads();
        lds[t] += u;
        __syncthreads();
    }
    if (t < nb) bsum[t] = lds[t] - v;
}

__global__ __launch_bounds__(256) void k_add(int* __restrict__ rowp,
                                             int* __restrict__ cur,
                                             const int* __restrict__ bsum, int n,
                                             int e) {
    int t = threadIdx.x;
    int base = blockIdx.x * 1024 + t * 4;
    int off = bsum[blockIdx.x];
#pragma unroll
    for (int j = 0; j < 4; ++j) {
        int i = base + j;
        if (i < n) {
            int v = rowp[i] + off;
            rowp[i] = v;
            cur[i] = v;
        }
    }
    if (blockIdx.x == 0 && t == 0) rowp[n] = e;
}

__global__ void k_scatter(const int* __restrict__ src, const int* __restrict__ dst,
                          int* __restrict__ cur, int* __restrict__ csrc, int e) {
    int i = blockIdx.x * blockDim.x + threadIdx.x;
    if (i < e) {
        int p = atomicAdd(&cur[dst[i]], 1);
        csrc[p] = src[i];
    }
}

// ---------------- W pack: fp32 [128][128] -> fp16 frag-major ----------------
__global__ void k_pack(const float* __restrict__ Wk, const float* __restrict__ Wq,
                       const float* __restrict__ Wv, const float* __restrict__ Ws,
                       const float* __restrict__ Wfc1, ushort* __restrict__ Wp) {
    int id = blockIdx.y;
    const float* src;
    if (id < 8) {
        int m = id & 3, layer = id >> 2;
        src = (m == 0) ? Wk : (m == 1) ? Wq : (m == 2) ? Wv : Ws;
        src += layer * 16384;
    } else {
        src = Wfc1;
    }
    int o = blockIdx.x * 256 + threadIdx.x;
    int j = o & 7, l = (o >> 3) & 63, nf = (o >> 9) & 7, kc = o >> 12;
    int row = kc * 32 + ((l >> 4) << 3) + j;
    int col = nf * 16 + (l & 15);
    Wp[id * 16384 + o] = f2h(src[row * 128 + col]);
}

// ---------------- fc0: [N,16] @ [16,128] + b (fp32) ----------------
__global__ __launch_bounds__(256) void k_fc0(const float* __restrict__ X,
                                             const float* __restrict__ W,
                                             const float* __restrict__ b,
                                             float* __restrict__ H, int n) {
    __shared__ float Ws[16 * 128];
    __shared__ float xs[2][16];
    int t = threadIdx.x;
#pragma unroll
    for (int i = 0; i < 8; ++i) Ws[t + i * 256] = W[t + i * 256];
    if (t < 32) {
        int nn = blockIdx.x * 2 + (t >> 4);
        xs[t >> 4][t & 15] = (nn < n) ? X[nn * 16 + (t & 15)] : 0.f;
    }
    __syncthreads();
    int nd = blockIdx.x * 2 + (t >> 7);
    if (nd < n) {
        int c = t & 127;
        float acc = b[c];
#pragma unroll
        for (int j = 0; j < 16; ++j) acc += xs[t >> 7][j] * Ws[j * 128 + c];
        H[nd * 128 + c] = acc;
    }
}

// ---------------- MFMA GEMM: [N,128] @ [128,128] x nmat ----------------
__global__ __launch_bounds__(256) void k_gemm_mfma(
    const float* __restrict__ A, int n, const ushort* __restrict__ Wp,
    const float* __restrict__ b0, void* __restrict__ o0,
    const float* __restrict__ b1, void* __restrict__ o1,
    const float* __restrict__ b2, void* __restrict__ o2,
    const float* __restrict__ b3, void* __restrict__ o3,
    int flags, int nmat) {
    __shared__ ushort As[64 * 128];  // 16 KB
    char* Asb = (char*)As;
    int t = threadIdx.x;
    int rbase = blockIdx.x * 64;

#pragma unroll
    for (int i = 0; i < 8; ++i) {
        int f = t * 4 + i * 1024;
        int r = f >> 7, c = f & 127;
        float4 v = {0.f, 0.f, 0.f, 0.f};
        if (rbase + r < n) v = *(const float4*)&A[(size_t)(rbase + r) * 128 + c];
        ushort4 u;
        u.x = f2h(v.x); u.y = f2h(v.y); u.z = f2h(v.z); u.w = f2h(v.w);
        int byte = (r * 256 + c * 2) ^ ((r & 7) << 4);
        *(ushort4*)(Asb + byte) = u;
    }
    __syncthreads();

    int w = t >> 6, l = t & 63;
    int arow = w * 16 + (l & 15);
    int kq = l >> 4;

    f16x8 a[4];
#pragma unroll
    for (int kc = 0; kc < 4; ++kc) {
        int byte = (arow * 256 + kc * 64 + kq * 16) ^ ((arow & 7) << 4);
        a[kc] = *(const f16x8*)(Asb + byte);
    }

    for (int m = 0; m < nmat; ++m) {
        const float* bias; void* op;
        if (m == 0)      { bias = b0; op = o0; }
        else if (m == 1) { bias = b1; op = o1; }
        else if (m == 2) { bias = b2; op = o2; }
        else             { bias = b3; op = o3; }
        int isf16 = (flags >> m) & 1;
        int act   = (flags >> (8 + m)) & 1;
        const ushort* wb = Wp + m * 16384;

        f32x4 acc[8];
#pragma unroll
        for (int nf = 0; nf < 8; ++nf) acc[nf] = (f32x4){0.f, 0.f, 0.f, 0.f};

#pragma unroll
        for (int kc = 0; kc < 4; ++kc) {
#pragma unroll
            for (int nf = 0; nf < 8; ++nf) {
                f16x8 b = *(const f16x8*)(wb + (((kc * 8 + nf) * 64 + l) << 3));
                acc[nf] = __builtin_amdgcn_mfma_f32_16x16x32_f16(a[kc], b, acc[nf], 0, 0, 0);
            }
        }

#pragma unroll
        for (int nf = 0; nf < 8; ++nf) {
            int col = nf * 16 + (l & 15);
            float bia = bias[col];
#pragma unroll
            for (int r = 0; r < 4; ++r) {
                int row = rbase + w * 16 + (l >> 4) * 4 + r;
                if (row < n) {
                    float o = acc[nf][r] + bia;
                    if (act) o = gelu_f(o);
                    if (isf16) ((ushort*)op)[(size_t)row * 128 + col] = f2h(o);
                    else       ((float*)op)[(size_t)row * 128 + col] = o;
                }
            }
        }
    }
}

// ---------------- fused edge phase: one wave per dst node, 2 edges/iter ----
// lane = 64 lanes: hb = lane>>5 selects edge of pair; w = lane&31 holds
// features [w*4, w*4+4). Lanes 0-15: head0, 16-31: head1 (per half-wave).
// Branchless online softmax per half; halves merged via shfl_xor(32).
__global__ void k_edge_hf(const ushort* __restrict__ K, const ushort* __restrict__ Q,
                          const ushort* __restrict__ V, const int* __restrict__ rowp,
                          const int* __restrict__ csrc, float* __restrict__ H, int n,
                          int act) {
    int wid = (int)((blockIdx.x * blockDim.x + threadIdx.x) >> 6);
    int lane = threadIdx.x & 63;
    if (wid >= n) return;
    int hb = lane >> 5;       // which edge of the pair
    int w4 = (lane & 31) * 4; // feature base
    int e0 = rowp[wid], e1 = rowp[wid + 1];

    ushort4 qr = *(const ushort4*)&Q[(size_t)wid * 128 + w4];
    float q0 = h2f(qr.x), q1 = h2f(qr.y), q2 = h2f(qr.z), q3 = h2f(qr.w);

    float m = -1e30f;
    float denom = 0.f;
    float a0 = 0.f, a1 = 0.f, a2 = 0.f, a3 = 0.f;

    for (int eb = e0; eb < e1; eb += 64) {
        int cnt = min(64, e1 - eb);
        int sl = (eb + lane < e1) ? csrc[eb + lane] : 0;
        int jm = (cnt + 1) >> 1;
#pragma unroll 2
        for (int j = 0; j < jm; ++j) {
            int ei = 2 * j + hb;            // interleaved -> balanced halves
            bool val = ei < cnt;
            int s = __shfl(sl, ei);
            ushort4 kr = *(const ushort4*)&K[(size_t)s * 128 + w4];
            float sc = h2f(kr.x) * q0 + h2f(kr.y) * q1 + h2f(kr.z) * q2 +
                       h2f(kr.w) * q3;
            sc += __shfl_xor(sc, 1);
            sc += __shfl_xor(sc, 2);
            sc += __shfl_xor(sc, 4);
            sc += __shfl_xor(sc, 8);        // sum over 16-lane head group
            ushort4 vr = *(const ushort4*)&V[(size_t)s * 128 + w4];
            float mn = val ? fmaxf(m, sc) : m;
            float ss = __expf(m - mn);      // m==mn -> 1; first valid -> 0
            float p = val ? __expf(sc - mn) : 0.f;
            denom = denom * ss + p;
            a0 = a0 * ss + p * h2f(vr.x);
            a1 = a1 * ss + p * h2f(vr.y);
            a2 = a2 * ss + p * h2f(vr.z);
            a3 = a3 * ss + p * h2f(vr.w);
            m = mn;
        }
    }

    // merge the two half-wave softmax states (lane and lane^32 hold same feats)
    float mo = __shfl_xor(m, 32);
    float dn = __shfl_xor(denom, 32);
    float b0_ = __shfl_xor(a0, 32);
    float b1_ = __shfl_xor(a1, 32);
    float b2_ = __shfl_xor(a2, 32);
    float b3_ = __shfl_xor(a3, 32);
    float mn = fmaxf(m, mo);
    float sA = __expf(m - mn), sB = __expf(mo - mn);
    denom = denom * sA + dn * sB;
    a0 = a0 * sA + b0_ * sB;
    a1 = a1 * sA + b1_ * sB;
    a2 = a2 * sA + b2_ * sB;
    a3 = a3 * sA + b3_ * sB;

    if (lane < 32) {
        float inv = (denom > 0.f) ? 1.f / denom : 0.f;
        float4 h4 = *(float4*)&H[(size_t)wid * 128 + w4];
        float o0 = h4.x + a0 * inv;
        float o1 = h4.y + a1 * inv;
        float o2 = h4.z + a2 * inv;
        float o3 = h4.w + a3 * inv;
        if (act) {
            o0 = gelu_f(o0);
            o1 = gelu_f(o1);
            o2 = gelu_f(o2);
            o3 = gelu_f(o3);
        }
        float4 o = {o0, o1, o2, o3};
        *(float4*)&H[(size_t)wid * 128 + w4] = o;
    }
}

// ---------------- fc2: fp16 [N,128] @ fp32 [128,4] + b ----------------
__global__ void k_fc2(const ushort* __restrict__ Hh, const float* __restrict__ W,
                      const float* __restrict__ b, float* __restrict__ out, int n) {
    int wid = (int)((blockIdx.x * blockDim.x + threadIdx.x) >> 6);
    int lane = threadIdx.x & 63;
    if (wid >= n) return;
    unsigned raw = *(const unsigned*)(Hh + (size_t)wid * 128 + lane * 2);
    float x0 = h2f((ushort)(raw & 0xffff)), x1 = h2f((ushort)(raw >> 16));
    float4 wA = *(const float4*)&W[(lane * 2) * 4];
    float4 wB = *(const float4*)&W[(lane * 2 + 1) * 4];
    float a0 = x0 * wA.x + x1 * wB.x;
    float a1 = x0 * wA.y + x1 * wB.y;
    float a2 = x0 * wA.z + x1 * wB.z;
    float a3 = x0 * wA.w + x1 * wB.w;
#pragma unroll
    for (int off = 1; off < 64; off <<= 1) {
        a0 += __shfl_xor(a0, off);
        a1 += __shfl_xor(a1, off);
        a2 += __shfl_xor(a2, off);
        a3 += __shfl_xor(a3, off);
    }
    if (lane < 4) {
        float v = (lane == 0) ? a0 : (lane == 1) ? a1 : (lane == 2) ? a2 : a3;
        out[(size_t)wid * 4 + lane] = v + b[lane];
    }
}

extern "C" void kernel_launch(void* const* d_in, const int* in_sizes, int n_in,
                              void* d_out, int out_size, void* d_ws, size_t ws_size,
                              hipStream_t stream) {
    const float* x     = (const float*)d_in[0];
    const int*   src   = (const int*)d_in[1];
    const int*   dst   = (const int*)d_in[2];
    const float* fc0_w = (const float*)d_in[3];
    const float* fc0_b = (const float*)d_in[4];
    const float* Wk    = (const float*)d_in[5];
    const float* bk    = (const float*)d_in[6];
    const float* Wq    = (const float*)d_in[7];
    const float* bq    = (const float*)d_in[8];
    const float* Wv    = (const float*)d_in[9];
    const float* bv    = (const float*)d_in[10];
    const float* ws_w  = (const float*)d_in[11];
    const float* ws_b  = (const float*)d_in[12];
    const float* fc1_w = (const float*)d_in[13];
    const float* fc1_b = (const float*)d_in[14];
    const float* fc2_w = (const float*)d_in[15];
    const float* fc2_b = (const float*)d_in[16];

    int n = in_sizes[0] / 16;
    int e = in_sizes[1];

    float*  hA  = (float*)d_ws;
    float*  hB  = hA + (size_t)n * 128;
    ushort* Kb  = (ushort*)(hB + (size_t)n * 128);
    ushort* Qb  = Kb + (size_t)n * 128;
    ushort* Vb  = Qb + (size_t)n * 128;
    ushort* Wp  = Vb + (size_t)n * 128;   // 9 * 16384 fp16
    int* deg    = (int*)(Wp + 9 * 16384);
    int* rowp   = deg + n;
    int* cur    = rowp + n + 1;
    int* csrc   = cur + n;
    int* bsum   = csrc + e;               // 128 ints scratch

    int nb = (n + 1023) / 1024;

    // CSR build
    k_zero<<<(n + 255) / 256, 256, 0, stream>>>(deg, n);
    k_hist<<<(e + 255) / 256, 256, 0, stream>>>(dst, deg, e);
    k_part<<<nb, 256, 0, stream>>>(deg, rowp, bsum, n);
    k_scanb<<<1, 128, 0, stream>>>(bsum, nb);
    k_add<<<nb, 256, 0, stream>>>(rowp, cur, bsum, n, e);
    k_scatter<<<(e + 255) / 256, 256, 0, stream>>>(src, dst, cur, csrc, e);

    // pack all 9 weight matrices to fp16 frag-major
    k_pack<<<dim3(64, 9), 256, 0, stream>>>(Wk, Wq, Wv, ws_w, fc1_w, Wp);

    // fc0 (fp32)
    k_fc0<<<(n + 1) / 2, 256, 0, stream>>>(x, fc0_w, fc0_b, hA, n);

    int gx = (n + 63) / 64;
    // layer 0: k,q,v -> fp16; ws -> fp32 into hB. Then edge (+gelu).
    k_gemm_mfma<<<gx, 256, 0, stream>>>(hA, n, Wp, bk, Kb, bq, Qb, bv, Vb, ws_b, hB,
                                        0x07, 4);
    k_edge_hf<<<(n + 3) / 4, 256, 0, stream>>>(Kb, Qb, Vb, rowp, csrc, hB, n, 1);
    // layer 1
    k_gemm_mfma<<<gx, 256, 0, stream>>>(hB, n, Wp + 4 * 16384, bk + 128, Kb, bq + 128,
                                        Qb, bv + 128, Vb, ws_b + 128, hA, 0x07, 4);
    k_edge_hf<<<(n + 3) / 4, 256, 0, stream>>>(Kb, Qb, Vb, rowp, csrc, hA, n, 0);

    // fc1 + gelu -> fp16 (reuse Kb)
    k_gemm_mfma<<<gx, 256, 0, stream>>>(hA, n, Wp + 8 * 16384, fc1_b, Kb, fc1_b, Kb,
                                        fc1_b, Kb, fc1_b, Kb, 0x101, 1);
    // fc2
    k_fc2<<<(n + 3) / 4, 256, 0, stream>>>(Kb, fc2_w, fc2_b, (float*)d_out, n);
}

// Round 8
// 590.676 us; speedup vs baseline: 2.3805x; 1.1856x over previous
//
#include <hip/hip_runtime.h>
#include <math.h>

// GAT forward. R7 = R6 with cvt_pkrtz return-type fix (bit_cast __fp16x2->h2).
//  (a) edge kernel: 4 edges/wave-iter (16 lanes/edge, 8 feats/lane), QK dot
//      via v_dot2_f32_f16 (fdot2), PV accumulate in packed fp16 (pk_fma),
//      p/ss packed via cvt_pkrtz -> ~3x fewer VALU ops/edge than R5.
//  (b) scatter: rank captured from k_hist's atomicAdd return (coalesced
//      write); k_scatter is now atomic-free gather+store.
// Structure: CSR build -> W pack (fp16 frag-major) -> fc0 (fp32) ->
//   2x [ gemm_mfma(k,q,v->fp16; ws->fp32) -> fused edge ] -> fc1 -> fc2.

typedef _Float16 f16x8 __attribute__((ext_vector_type(8)));
typedef _Float16 h2 __attribute__((ext_vector_type(2)));
typedef float f32x4 __attribute__((ext_vector_type(4)));

__device__ __forceinline__ ushort f2h(float x) {
    union { _Float16 h; ushort u; } v;
    v.h = (_Float16)x;
    return v.u;
}
__device__ __forceinline__ float h2f(ushort u) {
    union { ushort u; _Float16 h; } v;
    v.u = u;
    return (float)v.h;
}

__device__ __forceinline__ float gelu_f(float x) {
    float x3 = x * x * x;
    return 0.5f * x * (1.f + tanhf(0.7978845608028654f * (x + 0.044715f * x3)));
}

__device__ __forceinline__ h2 pk2(float a, float b) {
    return __builtin_bit_cast(h2, __builtin_amdgcn_cvt_pkrtz(a, b));
}

// ---------------- CSR build ----------------
__global__ void k_zero(int* __restrict__ p, int n) {
    int i = blockIdx.x * blockDim.x + threadIdx.x;
    if (i < n) p[i] = 0;
}

// histogram + per-edge rank (old value of the counter)
__global__ void k_hist(const int* __restrict__ dst, int* __restrict__ deg,
                       int* __restrict__ rank, int e) {
    int i = blockIdx.x * blockDim.x + threadIdx.x;
    if (i < e) rank[i] = atomicAdd(&deg[dst[i]], 1);
}

__global__ __launch_bounds__(256) void k_part(const int* __restrict__ deg,
                                              int* __restrict__ pre,
                                              int* __restrict__ bsum, int n) {
    __shared__ int lds[256];
    int t = threadIdx.x;
    int base = blockIdx.x * 1024 + t * 4;
    int d0 = 0, d1 = 0, d2 = 0, d3 = 0;
    if (base + 3 < n) {
        int4 d = *(const int4*)&deg[base];
        d0 = d.x; d1 = d.y; d2 = d.z; d3 = d.w;
    } else {
        if (base + 0 < n) d0 = deg[base + 0];
        if (base + 1 < n) d1 = deg[base + 1];
        if (base + 2 < n) d2 = deg[base + 2];
        if (base + 3 < n) d3 = deg[base + 3];
    }
    int s0 = d0, s1 = s0 + d1, s2 = s1 + d2, s3 = s2 + d3;
    lds[t] = s3;
    __syncthreads();
    for (int off = 1; off < 256; off <<= 1) {
        int v = (t >= off) ? lds[t - off] : 0;
        __syncthreads();
        lds[t] += v;
        __syncthreads();
    }
    int excl = lds[t] - s3;
    if (base + 0 < n) pre[base + 0] = excl;
    if (base + 1 < n) pre[base + 1] = excl + s0;
    if (base + 2 < n) pre[base + 2] = excl + s1;
    if (base + 3 < n) pre[base + 3] = excl + s2;
    if (t == 255) bsum[blockIdx.x] = lds[255];
}

__global__ void k_scanb(int* __restrict__ bsum, int nb) {
    __shared__ int lds[128];
    int t = threadIdx.x;
    int v = (t < nb) ? bsum[t] : 0;
    lds[t] = v;
    __syncthreads();
    for (int off = 1; off < 128; off <<= 1) {
        int u = (t >= off) ? lds[t - off] : 0;
        __syncthreads();
        lds[t] += u;
        __syncthreads();
    }
    if (t < nb) bsum[t] = lds[t] - v;
}

__global__ __launch_bounds__(256) void k_add(int* __restrict__ rowp,
                                             const int* __restrict__ bsum, int n,
                                             int e) {
    int t = threadIdx.x;
    int base = blockIdx.x * 1024 + t * 4;
    int off = bsum[blockIdx.x];
#pragma unroll
    for (int j = 0; j < 4; ++j) {
        int i = base + j;
        if (i < n) rowp[i] += off;
    }
    if (blockIdx.x == 0 && t == 0) rowp[n] = e;
}

// atomic-free scatter: position = rowp[dst] + rank
__global__ void k_scatter(const int* __restrict__ src, const int* __restrict__ dst,
                          const int* __restrict__ rank, const int* __restrict__ rowp,
                          int* __restrict__ csrc, int e) {
    int i = blockIdx.x * blockDim.x + threadIdx.x;
    if (i < e) csrc[rowp[dst[i]] + rank[i]] = src[i];
}

// ---------------- W pack: fp32 [128][128] -> fp16 frag-major ----------------
__global__ void k_pack(const float* __restrict__ Wk, const float* __restrict__ Wq,
                       const float* __restrict__ Wv, const float* __restrict__ Ws,
                       const float* __restrict__ Wfc1, ushort* __restrict__ Wp) {
    int id = blockIdx.y;
    const float* src;
    if (id < 8) {
        int m = id & 3, layer = id >> 2;
        src = (m == 0) ? Wk : (m == 1) ? Wq : (m == 2) ? Wv : Ws;
        src += layer * 16384;
    } else {
        src = Wfc1;
    }
    int o = blockIdx.x * 256 + threadIdx.x;
    int j = o & 7, l = (o >> 3) & 63, nf = (o >> 9) & 7, kc = o >> 12;
    int row = kc * 32 + ((l >> 4) << 3) + j;
    int col = nf * 16 + (l & 15);
    Wp[id * 16384 + o] = f2h(src[row * 128 + col]);
}

// ---------------- fc0: [N,16] @ [16,128] + b (fp32) ----------------
__global__ __launch_bounds__(256) void k_fc0(const float* __restrict__ X,
                                             const float* __restrict__ W,
                                             const float* __restrict__ b,
                                             float* __restrict__ H, int n) {
    __shared__ float Ws[16 * 128];
    __shared__ float xs[2][16];
    int t = threadIdx.x;
#pragma unroll
    for (int i = 0; i < 8; ++i) Ws[t + i * 256] = W[t + i * 256];
    if (t < 32) {
        int nn = blockIdx.x * 2 + (t >> 4);
        xs[t >> 4][t & 15] = (nn < n) ? X[nn * 16 + (t & 15)] : 0.f;
    }
    __syncthreads();
    int nd = blockIdx.x * 2 + (t >> 7);
    if (nd < n) {
        int c = t & 127;
        float acc = b[c];
#pragma unroll
        for (int j = 0; j < 16; ++j) acc += xs[t >> 7][j] * Ws[j * 128 + c];
        H[nd * 128 + c] = acc;
    }
}

// ---------------- MFMA GEMM: [N,128] @ [128,128] x nmat ----------------
__global__ __launch_bounds__(256) void k_gemm_mfma(
    const float* __restrict__ A, int n, const ushort* __restrict__ Wp,
    const float* __restrict__ b0, void* __restrict__ o0,
    const float* __restrict__ b1, void* __restrict__ o1,
    const float* __restrict__ b2, void* __restrict__ o2,
    const float* __restrict__ b3, void* __restrict__ o3,
    int flags, int nmat) {
    __shared__ ushort As[64 * 128];  // 16 KB
    char* Asb = (char*)As;
    int t = threadIdx.x;
    int rbase = blockIdx.x * 64;

#pragma unroll
    for (int i = 0; i < 8; ++i) {
        int f = t * 4 + i * 1024;
        int r = f >> 7, c = f & 127;
        float4 v = {0.f, 0.f, 0.f, 0.f};
        if (rbase + r < n) v = *(const float4*)&A[(size_t)(rbase + r) * 128 + c];
        ushort4 u;
        u.x = f2h(v.x); u.y = f2h(v.y); u.z = f2h(v.z); u.w = f2h(v.w);
        int byte = (r * 256 + c * 2) ^ ((r & 7) << 4);
        *(ushort4*)(Asb + byte) = u;
    }
    __syncthreads();

    int w = t >> 6, l = t & 63;
    int arow = w * 16 + (l & 15);
    int kq = l >> 4;

    f16x8 a[4];
#pragma unroll
    for (int kc = 0; kc < 4; ++kc) {
        int byte = (arow * 256 + kc * 64 + kq * 16) ^ ((arow & 7) << 4);
        a[kc] = *(const f16x8*)(Asb + byte);
    }

    for (int m = 0; m < nmat; ++m) {
        const float* bias; void* op;
        if (m == 0)      { bias = b0; op = o0; }
        else if (m == 1) { bias = b1; op = o1; }
        else if (m == 2) { bias = b2; op = o2; }
        else             { bias = b3; op = o3; }
        int isf16 = (flags >> m) & 1;
        int act   = (flags >> (8 + m)) & 1;
        const ushort* wb = Wp + m * 16384;

        f32x4 acc[8];
#pragma unroll
        for (int nf = 0; nf < 8; ++nf) acc[nf] = (f32x4){0.f, 0.f, 0.f, 0.f};

#pragma unroll
        for (int kc = 0; kc < 4; ++kc) {
#pragma unroll
            for (int nf = 0; nf < 8; ++nf) {
                f16x8 b = *(const f16x8*)(wb + (((kc * 8 + nf) * 64 + l) << 3));
                acc[nf] = __builtin_amdgcn_mfma_f32_16x16x32_f16(a[kc], b, acc[nf], 0, 0, 0);
            }
        }

#pragma unroll
        for (int nf = 0; nf < 8; ++nf) {
            int col = nf * 16 + (l & 15);
            float bia = bias[col];
#pragma unroll
            for (int r = 0; r < 4; ++r) {
                int row = rbase + w * 16 + (l >> 4) * 4 + r;
                if (row < n) {
                    float o = acc[nf][r] + bia;
                    if (act) o = gelu_f(o);
                    if (isf16) ((ushort*)op)[(size_t)row * 128 + col] = f2h(o);
                    else       ((float*)op)[(size_t)row * 128 + col] = o;
                }
            }
        }
    }
}

// ---------------- fused edge phase: one wave/dst node, 4 edges/iter --------
// quarter qb = lane>>4 owns edge slot; (lane&15) holds feats [w8, w8+8).
// Per quarter: lanes 0-7 = head0 (feats 0-63), 8-15 = head1 (feats 64-127).
// QK via fdot2 (fp32 acc), 3-shfl 8-lane head reduce, branchless online
// softmax, PV accumulate in packed fp16. Quarter states merged xor16/xor32.
__global__ void k_edge_hf(const ushort* __restrict__ K, const ushort* __restrict__ Q,
                          const ushort* __restrict__ V, const int* __restrict__ rowp,
                          const int* __restrict__ csrc, float* __restrict__ H, int n,
                          int act) {
    int wid = (int)((blockIdx.x * blockDim.x + threadIdx.x) >> 6);
    int lane = threadIdx.x & 63;
    if (wid >= n) return;
    int qb = lane >> 4;        // edge slot within quad
    int w8 = (lane & 15) * 8;  // feature base
    int e0 = rowp[wid], e1 = rowp[wid + 1];

    uint4 qr = *(const uint4*)&Q[(size_t)wid * 128 + w8];
    h2 q0 = __builtin_bit_cast(h2, qr.x), q1 = __builtin_bit_cast(h2, qr.y);
    h2 q2 = __builtin_bit_cast(h2, qr.z), q3 = __builtin_bit_cast(h2, qr.w);

    float m = -1e30f, denom = 0.f;
    h2 hz = {(_Float16)0.f, (_Float16)0.f};
    h2 acc0 = hz, acc1 = hz, acc2 = hz, acc3 = hz;

    for (int eb = e0; eb < e1; eb += 64) {
        int cnt = min(64, e1 - eb);
        int sl = (eb + lane < e1) ? csrc[eb + lane] : 0;
        int jm = (cnt + 3) >> 2;
#pragma unroll 2
        for (int j = 0; j < jm; ++j) {
            int ei = 4 * j + qb;  // interleaved -> balanced quarters
            bool val = ei < cnt;
            int s = __shfl(sl, ei);
            uint4 kr = *(const uint4*)&K[(size_t)s * 128 + w8];
            float sc = __builtin_amdgcn_fdot2(__builtin_bit_cast(h2, kr.x), q0,
                       __builtin_amdgcn_fdot2(__builtin_bit_cast(h2, kr.y), q1,
                       __builtin_amdgcn_fdot2(__builtin_bit_cast(h2, kr.z), q2,
                       __builtin_amdgcn_fdot2(__builtin_bit_cast(h2, kr.w), q3,
                                              0.f, false), false), false), false);
            sc += __shfl_xor(sc, 1);
            sc += __shfl_xor(sc, 2);
            sc += __shfl_xor(sc, 4);  // 8-lane head-group reduce
            uint4 vr = *(const uint4*)&V[(size_t)s * 128 + w8];
            float mn = val ? fmaxf(m, sc) : m;
            float ss = __expf(m - mn);     // first valid edge: exp(-huge)=0
            float p = val ? __expf(sc - mn) : 0.f;
            denom = denom * ss + p;
            h2 hp = pk2(p, p);
            h2 hs = pk2(ss, ss);
            acc0 = __builtin_bit_cast(h2, vr.x) * hp + acc0 * hs;
            acc1 = __builtin_bit_cast(h2, vr.y) * hp + acc1 * hs;
            acc2 = __builtin_bit_cast(h2, vr.z) * hp + acc2 * hs;
            acc3 = __builtin_bit_cast(h2, vr.w) * hp + acc3 * hs;
            m = mn;
        }
    }

    // to fp32 per-lane accumulator
    float a[8];
    a[0] = (float)acc0.x; a[1] = (float)acc0.y;
    a[2] = (float)acc1.x; a[3] = (float)acc1.y;
    a[4] = (float)acc2.x; a[5] = (float)acc2.y;
    a[6] = (float)acc3.x; a[7] = (float)acc3.y;

    // merge quarter states: lanes L, L^16, L^32, L^48 share (feats, head)
#pragma unroll
    for (int dist = 16; dist <= 32; dist <<= 1) {
        float mo = __shfl_xor(m, dist);
        float dn = __shfl_xor(denom, dist);
        float ao[8];
#pragma unroll
        for (int i = 0; i < 8; ++i) ao[i] = __shfl_xor(a[i], dist);
        float mn = fmaxf(m, mo);
        float sA = __expf(m - mn), sB = __expf(mo - mn);
        denom = denom * sA + dn * sB;
#pragma unroll
        for (int i = 0; i < 8; ++i) a[i] = a[i] * sA + ao[i] * sB;
        m = mn;
    }

    if (lane < 16) {
        float inv = (denom > 0.f) ? 1.f / denom : 0.f;
        float* hp = &H[(size_t)wid * 128 + w8];
        float4 h0 = *(float4*)hp;
        float4 h1 = *(float4*)(hp + 4);
        float o0 = h0.x + a[0] * inv, o1 = h0.y + a[1] * inv;
        float o2 = h0.z + a[2] * inv, o3 = h0.w + a[3] * inv;
        float o4 = h1.x + a[4] * inv, o5 = h1.y + a[5] * inv;
        float o6 = h1.z + a[6] * inv, o7 = h1.w + a[7] * inv;
        if (act) {
            o0 = gelu_f(o0); o1 = gelu_f(o1); o2 = gelu_f(o2); o3 = gelu_f(o3);
            o4 = gelu_f(o4); o5 = gelu_f(o5); o6 = gelu_f(o6); o7 = gelu_f(o7);
        }
        float4 w0 = {o0, o1, o2, o3};
        float4 w1 = {o4, o5, o6, o7};
        *(float4*)hp = w0;
        *(float4*)(hp + 4) = w1;
    }
}

// ---------------- fc2: fp16 [N,128] @ fp32 [128,4] + b ----------------
__global__ void k_fc2(const ushort* __restrict__ Hh, const float* __restrict__ W,
                      const float* __restrict__ b, float* __restrict__ out, int n) {
    int wid = (int)((blockIdx.x * blockDim.x + threadIdx.x) >> 6);
    int lane = threadIdx.x & 63;
    if (wid >= n) return;
    unsigned raw = *(const unsigned*)(Hh + (size_t)wid * 128 + lane * 2);
    float x0 = h2f((ushort)(raw & 0xffff)), x1 = h2f((ushort)(raw >> 16));
    float4 wA = *(const float4*)&W[(lane * 2) * 4];
    float4 wB = *(const float4*)&W[(lane * 2 + 1) * 4];
    float a0 = x0 * wA.x + x1 * wB.x;
    float a1 = x0 * wA.y + x1 * wB.y;
    float a2 = x0 * wA.z + x1 * wB.z;
    float a3 = x0 * wA.w + x1 * wB.w;
#pragma unroll
    for (int off = 1; off < 64; off <<= 1) {
        a0 += __shfl_xor(a0, off);
        a1 += __shfl_xor(a1, off);
        a2 += __shfl_xor(a2, off);
        a3 += __shfl_xor(a3, off);
    }
    if (lane < 4) {
        float v = (lane == 0) ? a0 : (lane == 1) ? a1 : (lane == 2) ? a2 : a3;
        out[(size_t)wid * 4 + lane] = v + b[lane];
    }
}

extern "C" void kernel_launch(void* const* d_in, const int* in_sizes, int n_in,
                              void* d_out, int out_size, void* d_ws, size_t ws_size,
                              hipStream_t stream) {
    const float* x     = (const float*)d_in[0];
    const int*   src   = (const int*)d_in[1];
    const int*   dst   = (const int*)d_in[2];
    const float* fc0_w = (const float*)d_in[3];
    const float* fc0_b = (const float*)d_in[4];
    const float* Wk    = (const float*)d_in[5];
    const float* bk    = (const float*)d_in[6];
    const float* Wq    = (const float*)d_in[7];
    const float* bq    = (const float*)d_in[8];
    const float* Wv    = (const float*)d_in[9];
    const float* bv    = (const float*)d_in[10];
    const float* ws_w  = (const float*)d_in[11];
    const float* ws_b  = (const float*)d_in[12];
    const float* fc1_w = (const float*)d_in[13];
    const float* fc1_b = (const float*)d_in[14];
    const float* fc2_w = (const float*)d_in[15];
    const float* fc2_b = (const float*)d_in[16];

    int n = in_sizes[0] / 16;
    int e = in_sizes[1];

    float*  hA  = (float*)d_ws;
    float*  hB  = hA + (size_t)n * 128;
    ushort* Kb  = (ushort*)(hB + (size_t)n * 128);
    ushort* Qb  = Kb + (size_t)n * 128;
    ushort* Vb  = Qb + (size_t)n * 128;
    ushort* Wp  = Vb + (size_t)n * 128;   // 9 * 16384 fp16
    int* deg    = (int*)(Wp + 9 * 16384);
    int* rowp   = deg + n;
    int* csrc   = rowp + n + 1;
    int* rank   = csrc + e;
    int* bsum   = rank + e;               // 128 ints scratch

    int nb = (n + 1023) / 1024;

    // CSR build
    k_zero<<<(n + 255) / 256, 256, 0, stream>>>(deg, n);
    k_hist<<<(e + 255) / 256, 256, 0, stream>>>(dst, deg, rank, e);
    k_part<<<nb, 256, 0, stream>>>(deg, rowp, bsum, n);
    k_scanb<<<1, 128, 0, stream>>>(bsum, nb);
    k_add<<<nb, 256, 0, stream>>>(rowp, bsum, n, e);
    k_scatter<<<(e + 255) / 256, 256, 0, stream>>>(src, dst, rank, rowp, csrc, e);

    // pack all 9 weight matrices to fp16 frag-major
    k_pack<<<dim3(64, 9), 256, 0, stream>>>(Wk, Wq, Wv, ws_w, fc1_w, Wp);

    // fc0 (fp32)
    k_fc0<<<(n + 1) / 2, 256, 0, stream>>>(x, fc0_w, fc0_b, hA, n);

    int gx = (n + 63) / 64;
    // layer 0: k,q,v -> fp16; ws -> fp32 into hB. Then edge (+gelu).
    k_gemm_mfma<<<gx, 256, 0, stream>>>(hA, n, Wp, bk, Kb, bq, Qb, bv, Vb, ws_b, hB,
                                        0x07, 4);
    k_edge_hf<<<(n + 3) / 4, 256, 0, stream>>>(Kb, Qb, Vb, rowp, csrc, hB, n, 1);
    // layer 1
    k_gemm_mfma<<<gx, 256, 0, stream>>>(hB, n, Wp + 4 * 16384, bk + 128, Kb, bq + 128,
                                        Qb, bv + 128, Vb, ws_b + 128, hA, 0x07, 4);
    k_edge_hf<<<(n + 3) / 4, 256, 0, stream>>>(Kb, Qb, Vb, rowp, csrc, hA, n, 0);

    // fc1 + gelu -> fp16 (reuse Kb)
    k_gemm_mfma<<<gx, 256, 0, stream>>>(hA, n, Wp + 8 * 16384, fc1_b, Kb, fc1_b, Kb,
                                        fc1_b, Kb, fc1_b, Kb, 0x101, 1);
    // fc2
    k_fc2<<<(n + 3) / 4, 256, 0, stream>>>(Kb, fc2_w, fc2_b, (float*)d_out, n);
}